// Round 1
// baseline (665.587 us; speedup 1.0000x reference)
//
#include <hip/hip_runtime.h>
#include <hip/hip_bf16.h>

// Problem constants (fixed by reference)
#define Bb 2
#define Vv 16
#define Hh 512
#define Ww 512
#define Kk 64      // P*P
#define Ee 1024
#define Ll 4096    // (H/P)*(W/P)

typedef __bf16 bf16x8 __attribute__((ext_vector_type(8)));
typedef float f32x4 __attribute__((ext_vector_type(4)));

#define LDSS 72    // 64 + 8 bf16 pad -> 144B row stride, 2-way bank alias (free)

__global__ __launch_bounds__(256) void patch_embed_kernel(
    const float* __restrict__ x, const int* __restrict__ vars,
    const float* __restrict__ pw, const float* __restrict__ pb,
    float* __restrict__ out)
{
    __shared__ __bf16 As[128 * LDSS];  // A: 128 patches x K=64
    __shared__ __bf16 Bs[128 * LDSS];  // B: 128 embed rows x K=64

    const int tid = threadIdx.x;
    const int nt  = blockIdx.x;   // 0..7   (E tiles of 128)
    const int mt  = blockIdx.y;   // 0..31  (L tiles of 128)
    const int bv  = blockIdx.z;   // 0..31  (b*V+v)
    const int v   = bv & (Vv - 1);
    const int var = vars[v];

    // ---- stage A: contiguous 16x512 slab of x == 128 patches x 64 K ----
    const float4* xp = (const float4*)(x + ((size_t)bv * Hh + (size_t)mt * 16) * Ww);
    #pragma unroll
    for (int i = 0; i < 8; i++) {
        int f = tid + i * 256;           // 0..2047 float4s
        float4 val = xp[f];
        int r  = f >> 7;                 // image row within slab (0..15)
        int c4 = f & 127;                // float4 col
        int l  = ((r >> 3) << 6) + (c4 >> 1);        // patch index
        int k  = ((r & 7) << 3) + ((c4 & 1) << 2);   // p*8+q
        __bf16* d = &As[l * LDSS + k];
        d[0] = (__bf16)val.x; d[1] = (__bf16)val.y;
        d[2] = (__bf16)val.z; d[3] = (__bf16)val.w;
    }
    // ---- stage B: gathered weight rows, 64 contiguous floats each ----
    const float4* wp = (const float4*)(pw + ((size_t)var * Ee + (size_t)nt * 128) * Kk);
    #pragma unroll
    for (int i = 0; i < 8; i++) {
        int f = tid + i * 256;
        float4 val = wp[f];
        int row = f >> 4;
        int k   = (f & 15) << 2;
        __bf16* d = &Bs[row * LDSS + k];
        d[0] = (__bf16)val.x; d[1] = (__bf16)val.y;
        d[2] = (__bf16)val.z; d[3] = (__bf16)val.w;
    }
    __syncthreads();

    const int lane = tid & 63;
    const int wv   = tid >> 6;
    const int wm   = (wv >> 1) << 6;   // wave row offset (0/64)
    const int wn   = (wv & 1) << 6;    // wave col offset (0/64)
    const int ln   = lane & 15;
    const int quad = lane >> 4;

    f32x4 acc[4][4] = {};
    #pragma unroll
    for (int kh = 0; kh < 2; kh++) {   // K=64 -> two K=32 MFMA steps
        bf16x8 af[4], bfr[4];
        #pragma unroll
        for (int mi = 0; mi < 4; mi++)
            af[mi] = *(const bf16x8*)&As[(wm + mi * 16 + ln) * LDSS + kh * 32 + quad * 8];
        #pragma unroll
        for (int nj = 0; nj < 4; nj++)
            bfr[nj] = *(const bf16x8*)&Bs[(wn + nj * 16 + ln) * LDSS + kh * 32 + quad * 8];
        #pragma unroll
        for (int mi = 0; mi < 4; mi++)
            #pragma unroll
            for (int nj = 0; nj < 4; nj++)
                acc[mi][nj] = __builtin_amdgcn_mfma_f32_16x16x32_bf16(
                    af[mi], bfr[nj], acc[mi][nj], 0, 0, 0);
    }

    // ---- epilogue: bias + store (D layout: col=lane&15, row=quad*4+reg) ----
    const float* bias = pb + (size_t)var * Ee;
    float bv4[4];
    #pragma unroll
    for (int nj = 0; nj < 4; nj++)
        bv4[nj] = bias[nt * 128 + wn + nj * 16 + ln];

    float* outp = out + (size_t)bv * Ll * Ee;
    #pragma unroll
    for (int mi = 0; mi < 4; mi++) {
        int m0 = mt * 128 + wm + mi * 16 + quad * 4;
        #pragma unroll
        for (int r = 0; r < 4; r++) {
            float* row = outp + (size_t)(m0 + r) * Ee + nt * 128 + wn + ln;
            #pragma unroll
            for (int nj = 0; nj < 4; nj++)
                row[nj * 16] = acc[mi][nj][r] + bv4[nj];
        }
    }
}

extern "C" void kernel_launch(void* const* d_in, const int* in_sizes, int n_in,
                              void* d_out, int out_size, void* d_ws, size_t ws_size,
                              hipStream_t stream) {
    const float* x    = (const float*)d_in[0];
    const int*   vars = (const int*)d_in[1];
    const float* pw   = (const float*)d_in[2];
    const float* pb   = (const float*)d_in[3];
    float* out = (float*)d_out;
    dim3 grid(Ee / 128, Ll / 128, Bb * Vv);   // 8 x 32 x 32
    dim3 block(256);
    hipLaunchKernelGGL(patch_embed_kernel, grid, block, 0, stream,
                       x, vars, pw, pb, out);
}

// Round 2
// 598.266 us; speedup vs baseline: 1.1125x; 1.1125x over previous
//
#include <hip/hip_runtime.h>
#include <hip/hip_bf16.h>

// Problem constants (fixed by reference)
#define Bb 2
#define Vv 16
#define Hh 512
#define Ww 512
#define Kk 64      // P*P
#define Ee 1024
#define Ll 4096    // (H/P)*(W/P)

typedef __bf16 bf16x8 __attribute__((ext_vector_type(8)));
typedef __bf16 bf16x4 __attribute__((ext_vector_type(4)));
typedef float f32x4 __attribute__((ext_vector_type(4)));

#define LDSS 72    // 64 + 8 bf16 pad -> 144B row stride (16B aligned), 2-way bank alias on b128 reads

__global__ __launch_bounds__(256) void patch_embed_kernel(
    const float* __restrict__ x, const int* __restrict__ vars,
    const float* __restrict__ pw, const float* __restrict__ pb,
    float* __restrict__ out)
{
    // M dim = E (weights feed the A operand), N dim = L (patches feed B).
    // D layout col=lane&15 -> L row of out, row=quad*4+reg -> 4 CONSECUTIVE E cols
    // => f32x4 vector stores.
    __shared__ __bf16 Xs[128 * LDSS];  // patches: 128 L x 64 K
    __shared__ __bf16 Wt[128 * LDSS];  // weights: 128 E x 64 K

    const int tid = threadIdx.x;
    const int nt  = blockIdx.x;   // 0..7   E tiles of 128
    const int mt  = blockIdx.y;   // 0..31  L tiles of 128
    const int bv  = blockIdx.z;   // 0..31  b*V+v
    const int v   = bv & (Vv - 1);
    const int var = vars[v];

    // ---- stage X: contiguous 16x512 slab of x == 128 patches x 64 K ----
    const float4* xp = (const float4*)(x + ((size_t)bv * Hh + (size_t)mt * 16) * Ww);
    #pragma unroll
    for (int i = 0; i < 8; i++) {
        int f = tid + i * 256;           // 0..2047 float4s
        float4 val = xp[f];
        int r  = f >> 7;                 // image row within slab (0..15)
        int c4 = f & 127;                // float4 col
        int l  = ((r >> 3) << 6) + (c4 >> 1);        // patch index
        int k  = ((r & 7) << 3) + ((c4 & 1) << 2);   // p*8+q
        bf16x4 pk = { (__bf16)val.x, (__bf16)val.y, (__bf16)val.z, (__bf16)val.w };
        *(bf16x4*)&Xs[l * LDSS + k] = pk;            // single ds_write_b64
    }
    // ---- stage W: gathered weight rows, 64 contiguous floats each ----
    const float4* wp = (const float4*)(pw + ((size_t)var * Ee + (size_t)nt * 128) * Kk);
    #pragma unroll
    for (int i = 0; i < 8; i++) {
        int f = tid + i * 256;
        float4 val = wp[f];
        int row = f >> 4;
        int k   = (f & 15) << 2;
        bf16x4 pk = { (__bf16)val.x, (__bf16)val.y, (__bf16)val.z, (__bf16)val.w };
        *(bf16x4*)&Wt[row * LDSS + k] = pk;
    }

    const int lane = tid & 63;
    const int wv   = tid >> 6;
    const int wE   = (wv >> 1) << 6;   // wave E offset (0/64)
    const int wL   = (wv & 1) << 6;    // wave L offset (0/64)
    const int ln   = lane & 15;
    const int quad = lane >> 4;

    // bias prefetch (E dim), overlaps the barrier
    const float4* b4 = (const float4*)(pb + (size_t)var * Ee + nt * 128 + wE + quad * 4);
    f32x4 bias4[4];
    #pragma unroll
    for (int mi = 0; mi < 4; mi++) {
        float4 t = b4[mi * 4];          // mi*16 floats apart
        f32x4 u = { t.x, t.y, t.z, t.w };
        bias4[mi] = u;
    }

    __syncthreads();

    f32x4 acc[4][4] = {};
    #pragma unroll
    for (int kh = 0; kh < 2; kh++) {   // K=64 -> two K=32 MFMA steps
        bf16x8 wf[4], xf[4];
        #pragma unroll
        for (int mi = 0; mi < 4; mi++)
            wf[mi] = *(const bf16x8*)&Wt[(wE + mi * 16 + ln) * LDSS + kh * 32 + quad * 8];
        #pragma unroll
        for (int nj = 0; nj < 4; nj++)
            xf[nj] = *(const bf16x8*)&Xs[(wL + nj * 16 + ln) * LDSS + kh * 32 + quad * 8];
        #pragma unroll
        for (int mi = 0; mi < 4; mi++)
            #pragma unroll
            for (int nj = 0; nj < 4; nj++)
                acc[mi][nj] = __builtin_amdgcn_mfma_f32_16x16x32_bf16(
                    wf[mi], xf[nj], acc[mi][nj], 0, 0, 0);
    }

    // ---- epilogue: bias + nontemporal f32x4 stores ----
    // lane ln = L row (out row), quad*4+reg = consecutive E cols -> 16B store
    float* outp = out + (size_t)bv * Ll * Ee;
    #pragma unroll
    for (int nj = 0; nj < 4; nj++) {
        size_t rowoff = (size_t)(mt * 128 + wL + nj * 16 + ln) * Ee
                      + (size_t)(nt * 128 + wE + quad * 4);
        #pragma unroll
        for (int mi = 0; mi < 4; mi++) {
            f32x4 val = acc[mi][nj] + bias4[mi];
            __builtin_nontemporal_store(val, (f32x4*)(outp + rowoff + mi * 16));
        }
    }
}

extern "C" void kernel_launch(void* const* d_in, const int* in_sizes, int n_in,
                              void* d_out, int out_size, void* d_ws, size_t ws_size,
                              hipStream_t stream) {
    const float* x    = (const float*)d_in[0];
    const int*   vars = (const int*)d_in[1];
    const float* pw   = (const float*)d_in[2];
    const float* pb   = (const float*)d_in[3];
    float* out = (float*)d_out;
    dim3 grid(Ee / 128, Ll / 128, Bb * Vv);   // 8 x 32 x 32
    dim3 block(256);
    hipLaunchKernelGGL(patch_embed_kernel, grid, block, 0, stream,
                       x, vars, pw, pb, out);
}